// Round 11
// baseline (108.524 us; speedup 1.0000x reference)
//
#include <hip/hip_runtime.h>

static constexpr int BATCH = 32768;

typedef short bf8 __attribute__((ext_vector_type(8)));   // 8 bf16 in 4 VGPRs (MFMA A/B frag)
typedef float f32x4 __attribute__((ext_vector_type(4))); // MFMA C/D frag
typedef unsigned short u16x4 __attribute__((ext_vector_type(4)));

#define MFMA16 __builtin_amdgcn_mfma_f32_16x16x32_bf16

// A[16M x 32K]: lane(g,c) holds row=c, k=g*8+e.  B[32K x 16N]: col=c, k=g*8+e.
// D[16M x 16N]: col=c, row=g*4+r.
// SWAPPED use: mfma(W_frag, h_frag) -> lane(g,c) = u[m=c][n=g*4+r] per n-tile.

__device__ __forceinline__ unsigned short f2bf(float f) {
    return __builtin_bit_cast(unsigned short, static_cast<__bf16>(f));
}
__device__ __forceinline__ float bf2f(unsigned short h) {
    return __uint_as_float(((unsigned)h) << 16);
}

// swizzled u16 index within a [rows][64] bf16 LDS tile (128B rows):
#define SWI(row, col)  ((row) * 64 + ((col) ^ (((row) & 7) << 3)))
#define LD8(buf, row, col8) (*(const bf8*)((buf) + (row) * 64 + 8 * ((col8) ^ ((row) & 7))))

// ---- ws layout (u16 elems) ----
// W02 = W0eff @ W2 (no nonlinearity between the two linears)
// [0,2048)        neWt    [64][32]  (k<16: merged neW; k==16: ne_b; else 0)
// [2048,10240)    w02t_1  [64][128]
// [10240,18432)   w02t_2  [64][128]
// [18432,22528)   pkwt    [64][64]  = pkW direct cast ([j][n] for swapped w-GEMM A)
// [22528,26624)   pqt     [64][64]  ([n][k] for q-GEMM B)
// [26624,28672)   headt   [32][64] (oh|c1|c2 packed, rest 0)
// floats: [14336,14368) headb; [14368,14432) b2eff_1; [14432,14496) b2eff_2
__global__ void __launch_bounds__(256) merge_all(
    const float* __restrict__ neW, const float* __restrict__ neA, const float* __restrict__ neB,
    const float* __restrict__ ne_b,
    const float* __restrict__ g1W0, const float* __restrict__ g1A, const float* __restrict__ g1B,
    const float* __restrict__ g1W2, const float* __restrict__ g1b0, const float* __restrict__ g1b2,
    const float* __restrict__ g2W0, const float* __restrict__ g2A, const float* __restrict__ g2B,
    const float* __restrict__ g2W2, const float* __restrict__ g2b0, const float* __restrict__ g2b2,
    const float* __restrict__ pkW, const float* __restrict__ pqW,
    const float* __restrict__ ohW, const float* __restrict__ c1W, const float* __restrict__ c2W,
    const float* __restrict__ ohb, const float* __restrict__ c1b, const float* __restrict__ c2b,
    unsigned short* __restrict__ ws) {
    int t = blockIdx.x * 256 + threadIdx.x;
    if (t >= 28832) return;
    if (t >= 28768) { // b2eff layer 2
        int n = t - 28768;
        float acc = g2b2[n];
        for (int k = 0; k < 64; ++k) acc = fmaf(g2b0[k], g2W2[k * 64 + n], acc);
        ((float*)ws)[14432 + n] = acc;
        return;
    }
    if (t >= 28704) { // b2eff layer 1
        int n = t - 28704;
        float acc = g1b2[n];
        for (int k = 0; k < 64; ++k) acc = fmaf(g1b0[k], g1W2[k * 64 + n], acc);
        ((float*)ws)[14368 + n] = acc;
        return;
    }
    if (t >= 28672) { // head bias (f32)
        int i = t - 28672;
        float v = 0.0f;
        if (i < 8) v = ohb[i]; else if (i < 18) v = c1b[i - 8]; else if (i < 28) v = c2b[i - 18];
        ((float*)ws)[14336 + i] = v;
        return;
    }
    float val = 0.0f;
    if (t < 2048) {
        int n = t >> 5, k = t & 31;
        if (k < 16) {
            val = neW[k * 64 + n];
            #pragma unroll
            for (int r = 0; r < 4; ++r) val = fmaf(neA[k * 4 + r], neB[r * 64 + n], val);
        } else if (k == 16) {
            val = ne_b[n];
        }
    } else if (t < 18432) {
        // w02t[n][k] = sum_j W0eff[k][j] * W2[j][n]
        int loc = t - 2048;
        const float *W0, *A, *Bm, *W2;
        if (loc < 8192) { W0 = g1W0; A = g1A; Bm = g1B; W2 = g1W2; }
        else { loc -= 8192; W0 = g2W0; A = g2A; Bm = g2B; W2 = g2W2; }
        int n = loc >> 7, k = loc & 127;
        float a0 = A[k * 4 + 0], a1 = A[k * 4 + 1], a2 = A[k * 4 + 2], a3 = A[k * 4 + 3];
        for (int j = 0; j < 64; ++j) {
            float w0e = W0[k * 64 + j];
            w0e = fmaf(a0, Bm[0 * 64 + j], w0e);
            w0e = fmaf(a1, Bm[1 * 64 + j], w0e);
            w0e = fmaf(a2, Bm[2 * 64 + j], w0e);
            w0e = fmaf(a3, Bm[3 * 64 + j], w0e);
            val = fmaf(w0e, W2[j * 64 + n], val);
        }
    } else if (t < 22528) {
        val = pkW[t - 18432];   // direct cast: pkwt[j][n] = pkW[j][n]
    } else if (t < 26624) {
        int loc = t - 22528; int n = loc >> 6, k = loc & 63;
        val = pqW[k * 64 + n];
    } else {
        int loc = t - 26624; int n = loc >> 6, k = loc & 63;
        if (n < 8) val = ohW[k * 8 + n];
        else if (n < 18) val = c1W[k * 10 + (n - 8)];
        else if (n < 28) val = c2W[k * 10 + (n - 18)];
    }
    ws[t] = f2bf(val);
}

__device__ __forceinline__ int nc_sel(int4 nc, int bb) {
    int lo = (bb & 1) ? nc.y : nc.x;
    int hi = (bb & 1) ? nc.w : nc.z;
    return (bb & 2) ? hi : lo;
}

// Per-wave mean over the wave's 4 batches. lane (g,c): batch g, cols 4c..4c+3.
__device__ __forceinline__ void wave_mean(
    const unsigned short* hbuf, unsigned short* msgbuf, float* out4,
    int4 nc, int b0, int g, int c) {
    int c4 = c * 4;
    float s0 = 0, s1 = 0, s2 = 0, s3 = 0;
    int base = g * 20;
    #pragma unroll
    for (int n = 0; n < 20; ++n) {
        int row = base + n;
        u16x4 v = *(const u16x4*)(hbuf + SWI(row, c4));
        s0 += bf2f(v[0]); s1 += bf2f(v[1]); s2 += bf2f(v[2]); s3 += bf2f(v[3]);
    }
    float ic = 1.0f / (float)nc_sel(nc, g);
    s0 *= ic; s1 *= ic; s2 *= ic; s3 *= ic;
    u16x4 o; o[0] = f2bf(s0); o[1] = f2bf(s1); o[2] = f2bf(s2); o[3] = f2bf(s3);
    *(u16x4*)(msgbuf + SWI(g, c4)) = o;
    if (out4) {
        f32x4 fo = {s0, s1, s2, s3};
        *(f32x4*)(out4 + (size_t)(b0 + g) * 64 + c4) = fo;
    }
}

// One GNN layer, swapped orientation, 2-deep A-frag prefetch.
__device__ __forceinline__ void gnn_layer_sw(
    unsigned short* hbuf, unsigned short* msgbuf,
    const unsigned short* __restrict__ w02t,
    const float* __restrict__ b2e, const float* __restrict__ gmp, const float* __restrict__ btp,
    int4 nc, unsigned vmask, int b0, int g, int c) {
    wave_mean(hbuf, msgbuf, nullptr, nc, b0, g, c);
    const int nb = g * 4;

    // prologue: fragments for mt=0 (rA=c<16 -> batch 0)
    bf8 h0 = LD8(hbuf, c, 0 + g);
    bf8 h1 = LD8(hbuf, c, 4 + g);
    bf8 m0 = LD8(msgbuf, 0, 0 + g);
    bf8 m1 = LD8(msgbuf, 0, 4 + g);

    #pragma unroll 1
    for (int mt = 0; mt < 5; ++mt) {
        int rA = mt * 16 + c;
        f32x4 du[4];
        #pragma unroll
        for (int nt = 0; nt < 4; ++nt) du[nt] = (f32x4){0.f, 0.f, 0.f, 0.f};
        #pragma unroll
        for (int nt = 0; nt < 4; ++nt) {
            const unsigned short* wp = w02t + (nt * 16 + c) * 128 + g * 8;
            du[nt] = MFMA16(*(const bf8*)(wp), h0, du[nt], 0, 0, 0);      // swapped: A=W
            du[nt] = MFMA16(*(const bf8*)(wp + 32), h1, du[nt], 0, 0, 0);
            du[nt] = MFMA16(*(const bf8*)(wp + 64), m0, du[nt], 0, 0, 0);
            du[nt] = MFMA16(*(const bf8*)(wp + 96), m1, du[nt], 0, 0, 0);
        }
        // prefetch next tile's fragments (distinct rows from this tile's writes)
        if (mt < 4) {
            int rN = rA + 16;
            int bN = (rN >= 20) + (rN >= 40) + (rN >= 60);
            h0 = LD8(hbuf, rN, 0 + g);
            h1 = LD8(hbuf, rN, 4 + g);
            m0 = LD8(msgbuf, bN, 0 + g);
            m1 = LD8(msgbuf, bN, 4 + g);
        }
        // epilogue: lane has u[rA][nt*16+nb+r]. v = h + relu(u+b2e); LN over row; write h'
        float vv[16];
        float ps = 0.f, pq = 0.f;
        #pragma unroll
        for (int nt = 0; nt < 4; ++nt) {
            f32x4 b4 = *(const f32x4*)(b2e + nt * 16 + nb);
            u16x4 h4 = *(const u16x4*)(hbuf + SWI(rA, nt * 16 + nb));
            #pragma unroll
            for (int r = 0; r < 4; ++r) {
                float u = du[nt][r] + b4[r];
                float v = bf2f(h4[r]) + fmaxf(u, 0.f);
                vv[nt * 4 + r] = v;
                ps += v; pq += v * v;
            }
        }
        ps += __shfl_xor(ps, 16, 64); ps += __shfl_xor(ps, 32, 64);
        pq += __shfl_xor(pq, 16, 64); pq += __shfl_xor(pq, 32, 64);
        float mu = ps * 0.015625f;
        float var = pq * 0.015625f - mu * mu;
        float rstd = rsqrtf(var + 1e-5f);
        bool valid = (vmask >> mt) & 1u;
        #pragma unroll
        for (int nt = 0; nt < 4; ++nt) {
            f32x4 g4 = *(const f32x4*)(gmp + nt * 16 + nb);
            f32x4 t4 = *(const f32x4*)(btp + nt * 16 + nb);
            u16x4 o;
            #pragma unroll
            for (int r = 0; r < 4; ++r) {
                float hn = (vv[nt * 4 + r] - mu) * rstd * g4[r] + t4[r];
                o[r] = f2bf(valid ? hn : 0.f);
            }
            *(u16x4*)(hbuf + SWI(rA, nt * 16 + nb)) = o;
        }
    }
}

__global__ void __launch_bounds__(64) gnn_main(
    const float* __restrict__ nf, const int* __restrict__ nn_c,
    const unsigned short* __restrict__ W,
    const float* __restrict__ n1g, const float* __restrict__ n1b,
    const float* __restrict__ n2g, const float* __restrict__ n2b,
    const float* __restrict__ pqb, const float* __restrict__ pkb,
    float* __restrict__ out) {
    __shared__ __align__(16) unsigned short hbuf[80 * 64];
    __shared__ __align__(16) unsigned short msgbuf[4 * 64];
    __shared__ __align__(16) unsigned short qbufh[4 * 64];  // q bf16, plain [4][64]
    __shared__ __align__(16) float wbuf[4 * 72];            // w[b][j] f32 (+[b][64]=q.pkb)

    const int lane = threadIdx.x & 63;
    const int g = lane >> 4, c = lane & 15;
    const int nb = g * 4;
    const int b0 = blockIdx.x * 4;
    const long grow0 = (long)b0 * 20;

    const unsigned short* neWt  = W;
    const unsigned short* w02t1 = W + 2048;
    const unsigned short* w02t2 = W + 10240;
    const unsigned short* pkwt  = W + 18432;
    const unsigned short* pqt   = W + 22528;
    const unsigned short* hdt   = W + 26624;
    const float* wsf = (const float*)W;
    const float* headb = wsf + 14336;

    const size_t OUT1 = (size_t)BATCH * 8,  OUT2 = (size_t)BATCH * 18;
    const size_t OUT3 = (size_t)BATCH * 28, OUT4 = (size_t)BATCH * 48;

    int4 nc;
    nc.x = nn_c[b0 + 0]; nc.y = nn_c[b0 + 1];
    nc.z = nn_c[b0 + 2]; nc.w = nn_c[b0 + 3];

    unsigned vmask = 0;   // bit mt: row mt*16+c valid

    // ---- embed (swapped): lane (g,c) owns row rA ----
    {
        bf8 bne[4];
        #pragma unroll
        for (int nt = 0; nt < 4; ++nt)
            bne[nt] = *(const bf8*)(neWt + (nt * 16 + c) * 32 + g * 8);
        #pragma unroll 1
        for (int mt = 0; mt < 5; ++mt) {
            int rA = mt * 16 + c;
            int bq = (rA >= 20) + (rA >= 40) + (rA >= 60);
            bf8 b = (bf8){0, 0, 0, 0, 0, 0, 0, 0};
            if (g < 2) {
                const f32x4* p4 = (const f32x4*)(nf + (grow0 + rA) * 16 + g * 8);
                f32x4 x = p4[0], y = p4[1];
                b[0] = (short)f2bf(x[0]); b[1] = (short)f2bf(x[1]);
                b[2] = (short)f2bf(x[2]); b[3] = (short)f2bf(x[3]);
                b[4] = (short)f2bf(y[0]); b[5] = (short)f2bf(y[1]);
                b[6] = (short)f2bf(y[2]); b[7] = (short)f2bf(y[3]);
            } else if (g == 2) {
                b[0] = (short)0x3F80;  // k=16 row: +ne_b
            }
            f32x4 acc[4];
            #pragma unroll
            for (int nt = 0; nt < 4; ++nt) acc[nt] = (f32x4){0.f, 0.f, 0.f, 0.f};
            #pragma unroll
            for (int nt = 0; nt < 4; ++nt) acc[nt] = MFMA16(bne[nt], b, acc[nt], 0, 0, 0); // swapped
            bool valid = (rA - bq * 20) < nc_sel(nc, bq);
            vmask |= (valid ? 1u : 0u) << mt;
            #pragma unroll
            for (int nt = 0; nt < 4; ++nt) {
                u16x4 o;
                #pragma unroll
                for (int r = 0; r < 4; ++r) o[r] = f2bf(valid ? acc[nt][r] : 0.f);
                *(u16x4*)(hbuf + SWI(rA, nt * 16 + nb)) = o;
            }
        }
    }

    // ---- layers (wave-local, swapped, prefetched) ----
    gnn_layer_sw(hbuf, msgbuf, w02t1, wsf + 14368, n1g, n1b, nc, vmask, b0, g, c);
    gnn_layer_sw(hbuf, msgbuf, w02t2, wsf + 14432, n2g, n2b, nc, vmask, b0, g, c);

    // ---- g = masked mean; writes msgbuf (bf16) + out4 (f32) ----
    wave_mean(hbuf, msgbuf, out + OUT4, nc, b0, g, c);

    // ---- q + heads (normal orientation; D rows = batches) ----
    {
        bf8 a0 = LD8(msgbuf, (c & 3), 0 + g);
        bf8 a1 = LD8(msgbuf, (c & 3), 4 + g);
        f32x4 dq[4];
        #pragma unroll
        for (int nt = 0; nt < 4; ++nt) dq[nt] = (f32x4){0.f, 0.f, 0.f, 0.f};
        #pragma unroll
        for (int nt = 0; nt < 4; ++nt) {
            const unsigned short* wp = pqt + (nt * 16 + c) * 64 + g * 8;
            dq[nt] = MFMA16(a0, *(const bf8*)(wp), dq[nt], 0, 0, 0);
            dq[nt] = MFMA16(a1, *(const bf8*)(wp + 32), dq[nt], 0, 0, 0);
        }
        f32x4 dh[2];
        #pragma unroll
        for (int nt = 0; nt < 2; ++nt) dh[nt] = (f32x4){0.f, 0.f, 0.f, 0.f};
        #pragma unroll
        for (int nt = 0; nt < 2; ++nt) {
            const unsigned short* wp = hdt + (nt * 16 + c) * 64 + g * 8;
            dh[nt] = MFMA16(a0, *(const bf8*)(wp), dh[nt], 0, 0, 0);
            dh[nt] = MFMA16(a1, *(const bf8*)(wp + 32), dh[nt], 0, 0, 0);
        }
        if (g == 0) {   // D rows 0..3 = this wave's batches r
            #pragma unroll
            for (int r = 0; r < 4; ++r) {
                #pragma unroll
                for (int nt = 0; nt < 4; ++nt)
                    qbufh[r * 64 + nt * 16 + c] = f2bf(dq[nt][r] + pqb[nt * 16 + c]);
                size_t ob = (size_t)(b0 + r);
                #pragma unroll
                for (int nt = 0; nt < 2; ++nt) {
                    int col = nt * 16 + c;
                    float v = dh[nt][r] + headb[col];
                    if (col < 8)       out[ob * 8 + col] = v;
                    else if (col < 18) out[OUT1 + ob * 10 + (col - 8)] = v;
                    else if (col < 28) out[OUT2 + ob * 10 + (col - 18)] = v;
                }
            }
        }
    }

    // ---- w[b] = pkW @ q[b] (8 MFMA, swapped) + plc[b] = q.pkb ----
    {
        bf8 qb0 = *(const bf8*)(qbufh + (c & 3) * 64 + g * 8);
        bf8 qb1 = *(const bf8*)(qbufh + (c & 3) * 64 + 32 + g * 8);
        #pragma unroll
        for (int jt = 0; jt < 4; ++jt) {
            const unsigned short* wp = pkwt + (jt * 16 + c) * 64 + g * 8;
            f32x4 dw = (f32x4){0.f, 0.f, 0.f, 0.f};
            dw = MFMA16(*(const bf8*)(wp), qb0, dw, 0, 0, 0);       // swapped: A=pkW rows j
            dw = MFMA16(*(const bf8*)(wp + 32), qb1, dw, 0, 0, 0);
            // lane(g,c): w[batch=c&3][j = jt*16+g*4+r]; lanes c,c+4,c+8,c+12 identical
            if (c < 4)
                *(f32x4*)(wbuf + c * 72 + jt * 16 + g * 4) = dw;
        }
        // plc[b] = q[b].pkb : lane (g,c) does 4-elem slice of batch g, butterfly over c
        u16x4 q4 = *(const u16x4*)(qbufh + g * 64 + c * 4);
        f32x4 p4 = *(const f32x4*)(pkb + c * 4);
        float plc = bf2f(q4[0]) * p4[0];
        plc = fmaf(bf2f(q4[1]), p4[1], plc);
        plc = fmaf(bf2f(q4[2]), p4[2], plc);
        plc = fmaf(bf2f(q4[3]), p4[3], plc);
        plc += __shfl_xor(plc, 1, 64);
        plc += __shfl_xor(plc, 2, 64);
        plc += __shfl_xor(plc, 4, 64);
        plc += __shfl_xor(plc, 8, 64);
        if (c == 0) wbuf[g * 72 + 64] = plc;
    }

    // ---- pl[row] = h'[row].w[bA] + plc[bA] (no MFMA, in-lane dot) ----
    {
        #pragma unroll 1
        for (int mt = 0; mt < 5; ++mt) {
            int rA = mt * 16 + c;
            int bA = (rA >= 20) + (rA >= 40) + (rA >= 60);
            float pl = wbuf[bA * 72 + 64];
            #pragma unroll
            for (int nt = 0; nt < 4; ++nt) {
                u16x4 h4 = *(const u16x4*)(hbuf + SWI(rA, nt * 16 + nb));
                f32x4 w4 = *(const f32x4*)(wbuf + bA * 72 + nt * 16 + nb);
                #pragma unroll
                for (int r = 0; r < 4; ++r)
                    pl = fmaf(bf2f(h4[r]), w4[r], pl);
            }
            pl += __shfl_xor(pl, 16, 64);
            pl += __shfl_xor(pl, 32, 64);
            if (g == 0) {
                bool valid = (vmask >> mt) & 1u;
                out[OUT3 + (size_t)(grow0 + rA)] = valid ? pl : -1e9f;
            }
        }
    }
}

extern "C" void kernel_launch(void* const* d_in, const int* in_sizes, int n_in,
                              void* d_out, int out_size, void* d_ws, size_t ws_size,
                              hipStream_t stream) {
    const float* nf   = (const float*)d_in[0];
    const int*   nn_c = (const int*)d_in[1];
    const float* neW  = (const float*)d_in[2];
    const float* ne_b = (const float*)d_in[3];
    const float* neA  = (const float*)d_in[4];
    const float* neB  = (const float*)d_in[5];
    const float* g1W0 = (const float*)d_in[6];
    const float* g1b0 = (const float*)d_in[7];
    const float* g1A  = (const float*)d_in[8];
    const float* g1B  = (const float*)d_in[9];
    const float* g1W2 = (const float*)d_in[10];
    const float* g1b2 = (const float*)d_in[11];
    const float* g2W0 = (const float*)d_in[12];
    const float* g2b0 = (const float*)d_in[13];
    const float* g2A  = (const float*)d_in[14];
    const float* g2B  = (const float*)d_in[15];
    const float* g2W2 = (const float*)d_in[16];
    const float* g2b2 = (const float*)d_in[17];
    const float* n1g  = (const float*)d_in[18];
    const float* n1b  = (const float*)d_in[19];
    const float* n2g  = (const float*)d_in[20];
    const float* n2b  = (const float*)d_in[21];
    const float* ohW  = (const float*)d_in[22];
    const float* ohb  = (const float*)d_in[23];
    const float* c1W  = (const float*)d_in[24];
    const float* c1b  = (const float*)d_in[25];
    const float* c2W  = (const float*)d_in[26];
    const float* c2b  = (const float*)d_in[27];
    const float* pqW  = (const float*)d_in[28];
    const float* pqb  = (const float*)d_in[29];
    const float* pkW  = (const float*)d_in[30];
    const float* pkb  = (const float*)d_in[31];
    unsigned short* ws = (unsigned short*)d_ws;
    float* out = (float*)d_out;

    merge_all<<<113, 256, 0, stream>>>(neW, neA, neB, ne_b,
                                       g1W0, g1A, g1B, g1W2, g1b0, g1b2,
                                       g2W0, g2A, g2B, g2W2, g2b0, g2b2,
                                       pkW, pqW, ohW, c1W, c2W,
                                       ohb, c1b, c2b, ws);
    gnn_main<<<BATCH / 4, 64, 0, stream>>>(nf, nn_c, ws,
                                           n1g, n1b, n2g, n2b,
                                           pqb, pkb, out);
}

// Round 12
// 103.629 us; speedup vs baseline: 1.0472x; 1.0472x over previous
//
#include <hip/hip_runtime.h>

static constexpr int BATCH = 32768;

typedef short bf8 __attribute__((ext_vector_type(8)));   // 8 bf16 in 4 VGPRs (MFMA A/B frag)
typedef float f32x4 __attribute__((ext_vector_type(4))); // MFMA C/D frag
typedef unsigned short u16x4 __attribute__((ext_vector_type(4)));

#define MFMA16 __builtin_amdgcn_mfma_f32_16x16x32_bf16

// A[16M x 32K]: lane(g,c) holds row=c, k=g*8+e.  B[32K x 16N]: col=c, k=g*8+e.
// D[16M x 16N]: col=c, row=g*4+r.
// SWAPPED use: mfma(W_frag, h_frag) -> lane(g,c) = u[m=c][n=g*4+r] per n-tile.

__device__ __forceinline__ unsigned short f2bf(float f) {
    return __builtin_bit_cast(unsigned short, static_cast<__bf16>(f));
}
__device__ __forceinline__ float bf2f(unsigned short h) {
    return __uint_as_float(((unsigned)h) << 16);
}

// swizzled u16 index within a [rows][64] bf16 LDS tile (128B rows):
#define SWI(row, col)  ((row) * 64 + ((col) ^ (((row) & 7) << 3)))
#define LD8(buf, row, col8) (*(const bf8*)((buf) + (row) * 64 + 8 * ((col8) ^ ((row) & 7))))

// ---- ws layout (u16 elems): weights [N][K] bf16 ----
// W02 = W0eff @ W2 (no nonlinearity between the two linears)
// [0,2048)        neWt    [64][32]  (k<16: merged neW; k==16: ne_b; else 0)
// [2048,10240)    w02t_1  [64][128]
// [10240,18432)   w02t_2  [64][128]
// [18432,22528)   pkt     [64][64]
// [22528,26624)   pqt     [64][64]
// [26624,28672)   headt   [32][64] (oh|c1|c2 packed, rest 0)
// floats: [14336,14368) headb; [14368,14432) b2eff_1; [14432,14496) b2eff_2
__global__ void __launch_bounds__(256) merge_all(
    const float* __restrict__ neW, const float* __restrict__ neA, const float* __restrict__ neB,
    const float* __restrict__ ne_b,
    const float* __restrict__ g1W0, const float* __restrict__ g1A, const float* __restrict__ g1B,
    const float* __restrict__ g1W2, const float* __restrict__ g1b0, const float* __restrict__ g1b2,
    const float* __restrict__ g2W0, const float* __restrict__ g2A, const float* __restrict__ g2B,
    const float* __restrict__ g2W2, const float* __restrict__ g2b0, const float* __restrict__ g2b2,
    const float* __restrict__ pkW, const float* __restrict__ pqW,
    const float* __restrict__ ohW, const float* __restrict__ c1W, const float* __restrict__ c2W,
    const float* __restrict__ ohb, const float* __restrict__ c1b, const float* __restrict__ c2b,
    unsigned short* __restrict__ ws) {
    int t = blockIdx.x * 256 + threadIdx.x;
    if (t >= 28832) return;
    if (t >= 28768) { // b2eff layer 2
        int n = t - 28768;
        float acc = g2b2[n];
        for (int k = 0; k < 64; ++k) acc = fmaf(g2b0[k], g2W2[k * 64 + n], acc);
        ((float*)ws)[14432 + n] = acc;
        return;
    }
    if (t >= 28704) { // b2eff layer 1
        int n = t - 28704;
        float acc = g1b2[n];
        for (int k = 0; k < 64; ++k) acc = fmaf(g1b0[k], g1W2[k * 64 + n], acc);
        ((float*)ws)[14368 + n] = acc;
        return;
    }
    if (t >= 28672) { // head bias (f32)
        int i = t - 28672;
        float v = 0.0f;
        if (i < 8) v = ohb[i]; else if (i < 18) v = c1b[i - 8]; else if (i < 28) v = c2b[i - 18];
        ((float*)ws)[14336 + i] = v;
        return;
    }
    float val = 0.0f;
    if (t < 2048) {
        int n = t >> 5, k = t & 31;
        if (k < 16) {
            val = neW[k * 64 + n];
            #pragma unroll
            for (int r = 0; r < 4; ++r) val = fmaf(neA[k * 4 + r], neB[r * 64 + n], val);
        } else if (k == 16) {
            val = ne_b[n];
        }
    } else if (t < 18432) {
        // w02t[n][k] = sum_j W0eff[k][j] * W2[j][n]
        int loc = t - 2048;
        const float *W0, *A, *Bm, *W2;
        if (loc < 8192) { W0 = g1W0; A = g1A; Bm = g1B; W2 = g1W2; }
        else { loc -= 8192; W0 = g2W0; A = g2A; Bm = g2B; W2 = g2W2; }
        int n = loc >> 7, k = loc & 127;
        float a0 = A[k * 4 + 0], a1 = A[k * 4 + 1], a2 = A[k * 4 + 2], a3 = A[k * 4 + 3];
        for (int j = 0; j < 64; ++j) {
            float w0e = W0[k * 64 + j];
            w0e = fmaf(a0, Bm[0 * 64 + j], w0e);
            w0e = fmaf(a1, Bm[1 * 64 + j], w0e);
            w0e = fmaf(a2, Bm[2 * 64 + j], w0e);
            w0e = fmaf(a3, Bm[3 * 64 + j], w0e);
            val = fmaf(w0e, W2[j * 64 + n], val);
        }
    } else if (t < 22528) {
        int loc = t - 18432; int n = loc >> 6, k = loc & 63;
        val = pkW[k * 64 + n];
    } else if (t < 26624) {
        int loc = t - 22528; int n = loc >> 6, k = loc & 63;
        val = pqW[k * 64 + n];
    } else {
        int loc = t - 26624; int n = loc >> 6, k = loc & 63;
        if (n < 8) val = ohW[k * 8 + n];
        else if (n < 18) val = c1W[k * 10 + (n - 8)];
        else if (n < 28) val = c2W[k * 10 + (n - 18)];
    }
    ws[t] = f2bf(val);
}

__device__ __forceinline__ int nc_sel(int4 nc, int bb) {
    int lo = (bb & 1) ? nc.y : nc.x;
    int hi = (bb & 1) ? nc.w : nc.z;
    return (bb & 2) ? hi : lo;
}

// Per-wave mean over the wave's 4 batches. lane (g,c): batch g, cols 4c..4c+3.
__device__ __forceinline__ void wave_mean(
    const unsigned short* hbuf, unsigned short* msgbuf, float* out4,
    int4 nc, int b0, int g, int c) {
    int c4 = c * 4;
    float s0 = 0, s1 = 0, s2 = 0, s3 = 0;
    int base = g * 20;
    #pragma unroll
    for (int n = 0; n < 20; ++n) {
        int row = base + n;
        u16x4 v = *(const u16x4*)(hbuf + SWI(row, c4));
        s0 += bf2f(v[0]); s1 += bf2f(v[1]); s2 += bf2f(v[2]); s3 += bf2f(v[3]);
    }
    float ic = 1.0f / (float)nc_sel(nc, g);
    s0 *= ic; s1 *= ic; s2 *= ic; s3 *= ic;
    u16x4 o; o[0] = f2bf(s0); o[1] = f2bf(s1); o[2] = f2bf(s2); o[3] = f2bf(s3);
    *(u16x4*)(msgbuf + SWI(g, c4)) = o;
    if (out4) {
        f32x4 fo = {s0, s1, s2, s3};
        *(f32x4*)(out4 + (size_t)(b0 + g) * 64 + c4) = fo;
    }
}

// One GNN layer, swapped orientation: lane (g,c) owns row m=mt*16+c.
// Epilogue reuses du in place (no separate vv array).
__device__ __forceinline__ void gnn_layer_sw(
    unsigned short* hbuf, unsigned short* msgbuf,
    const unsigned short* __restrict__ w02t,
    const float* __restrict__ b2e, const float* __restrict__ gmp, const float* __restrict__ btp,
    int4 nc, unsigned vmask, int b0, int g, int c) {
    wave_mean(hbuf, msgbuf, nullptr, nc, b0, g, c);
    const int nb = g * 4;

    #pragma unroll 1
    for (int mt = 0; mt < 5; ++mt) {
        int rA = mt * 16 + c;
        int bA = (rA >= 20) + (rA >= 40) + (rA >= 60);
        bf8 h0 = LD8(hbuf, rA, 0 + g);
        bf8 h1 = LD8(hbuf, rA, 4 + g);
        bf8 m0 = LD8(msgbuf, bA, 0 + g);
        bf8 m1 = LD8(msgbuf, bA, 4 + g);
        f32x4 du[4];
        #pragma unroll
        for (int nt = 0; nt < 4; ++nt) du[nt] = (f32x4){0.f, 0.f, 0.f, 0.f};
        #pragma unroll
        for (int nt = 0; nt < 4; ++nt) {
            const unsigned short* wp = w02t + (nt * 16 + c) * 128 + g * 8;
            du[nt] = MFMA16(*(const bf8*)(wp), h0, du[nt], 0, 0, 0);      // swapped: A=W
            du[nt] = MFMA16(*(const bf8*)(wp + 32), h1, du[nt], 0, 0, 0);
            du[nt] = MFMA16(*(const bf8*)(wp + 64), m0, du[nt], 0, 0, 0);
            du[nt] = MFMA16(*(const bf8*)(wp + 96), m1, du[nt], 0, 0, 0);
        }
        // epilogue: v = h + relu(u+b2e) overwrites du; LN over row; write h'
        float ps = 0.f, pq = 0.f;
        #pragma unroll
        for (int nt = 0; nt < 4; ++nt) {
            f32x4 b4 = *(const f32x4*)(b2e + nt * 16 + nb);
            u16x4 h4 = *(const u16x4*)(hbuf + SWI(rA, nt * 16 + nb));
            #pragma unroll
            for (int r = 0; r < 4; ++r) {
                float u = du[nt][r] + b4[r];
                float v = bf2f(h4[r]) + fmaxf(u, 0.f);
                du[nt][r] = v;
                ps += v; pq += v * v;
            }
        }
        ps += __shfl_xor(ps, 16, 64); ps += __shfl_xor(ps, 32, 64);
        pq += __shfl_xor(pq, 16, 64); pq += __shfl_xor(pq, 32, 64);
        float mu = ps * 0.015625f;
        float var = pq * 0.015625f - mu * mu;
        float rstd = rsqrtf(var + 1e-5f);
        bool valid = (vmask >> mt) & 1u;
        #pragma unroll
        for (int nt = 0; nt < 4; ++nt) {
            f32x4 g4 = *(const f32x4*)(gmp + nt * 16 + nb);
            f32x4 t4 = *(const f32x4*)(btp + nt * 16 + nb);
            u16x4 o;
            #pragma unroll
            for (int r = 0; r < 4; ++r) {
                float hn = (du[nt][r] - mu) * rstd * g4[r] + t4[r];
                o[r] = f2bf(valid ? hn : 0.f);
            }
            *(u16x4*)(hbuf + SWI(rA, nt * 16 + nb)) = o;
        }
    }
}

__global__ void __launch_bounds__(64) gnn_main(
    const float* __restrict__ nf, const int* __restrict__ nn_c,
    const unsigned short* __restrict__ W,
    const float* __restrict__ n1g, const float* __restrict__ n1b,
    const float* __restrict__ n2g, const float* __restrict__ n2b,
    const float* __restrict__ pqb, const float* __restrict__ pkb,
    float* __restrict__ out) {
    __shared__ __align__(16) unsigned short hbuf[80 * 64];
    __shared__ __align__(16) unsigned short msgbuf[4 * 64];
    __shared__ __align__(16) float qbuf[4 * 68];   // f32, row stride 68 (bank-spread)

    const int lane = threadIdx.x & 63;
    const int g = lane >> 4, c = lane & 15;
    const int nb = g * 4;
    const int b0 = blockIdx.x * 4;
    const long grow0 = (long)b0 * 20;

    const unsigned short* neWt  = W;
    const unsigned short* w02t1 = W + 2048;
    const unsigned short* w02t2 = W + 10240;
    const unsigned short* pkt   = W + 18432;
    const unsigned short* pqt   = W + 22528;
    const unsigned short* hdt   = W + 26624;
    const float* wsf = (const float*)W;
    const float* headb = wsf + 14336;

    const size_t OUT1 = (size_t)BATCH * 8,  OUT2 = (size_t)BATCH * 18;
    const size_t OUT3 = (size_t)BATCH * 28, OUT4 = (size_t)BATCH * 48;

    int4 nc;
    nc.x = nn_c[b0 + 0]; nc.y = nn_c[b0 + 1];
    nc.z = nn_c[b0 + 2]; nc.w = nn_c[b0 + 3];

    unsigned vmask = 0;   // bit mt: row mt*16+c valid

    // ---- embed (swapped), 2-deep nf load prefetch ----
    {
        bf8 bne[4];
        #pragma unroll
        for (int nt = 0; nt < 4; ++nt)
            bne[nt] = *(const bf8*)(neWt + (nt * 16 + c) * 32 + g * 8);
        f32x4 xc = (f32x4){0.f, 0.f, 0.f, 0.f}, yc = xc, xn = xc, yn = xc;
        if (g < 2) {
            const f32x4* p4 = (const f32x4*)(nf + (grow0 + c) * 16 + g * 8);
            xc = p4[0]; yc = p4[1];
        }
        #pragma unroll 1
        for (int mt = 0; mt < 5; ++mt) {
            int rA = mt * 16 + c;
            int bq = (rA >= 20) + (rA >= 40) + (rA >= 60);
            if (mt < 4 && g < 2) {
                const f32x4* p4 = (const f32x4*)(nf + (grow0 + rA + 16) * 16 + g * 8);
                xn = p4[0]; yn = p4[1];
            }
            bf8 b = (bf8){0, 0, 0, 0, 0, 0, 0, 0};
            if (g < 2) {
                b[0] = (short)f2bf(xc[0]); b[1] = (short)f2bf(xc[1]);
                b[2] = (short)f2bf(xc[2]); b[3] = (short)f2bf(xc[3]);
                b[4] = (short)f2bf(yc[0]); b[5] = (short)f2bf(yc[1]);
                b[6] = (short)f2bf(yc[2]); b[7] = (short)f2bf(yc[3]);
            } else if (g == 2) {
                b[0] = (short)0x3F80;  // k=16 row: +ne_b
            }
            f32x4 acc[4];
            #pragma unroll
            for (int nt = 0; nt < 4; ++nt) acc[nt] = (f32x4){0.f, 0.f, 0.f, 0.f};
            #pragma unroll
            for (int nt = 0; nt < 4; ++nt) acc[nt] = MFMA16(bne[nt], b, acc[nt], 0, 0, 0); // swapped
            bool valid = (rA - bq * 20) < nc_sel(nc, bq);
            vmask |= (valid ? 1u : 0u) << mt;
            #pragma unroll
            for (int nt = 0; nt < 4; ++nt) {
                u16x4 o;
                #pragma unroll
                for (int r = 0; r < 4; ++r) o[r] = f2bf(valid ? acc[nt][r] : 0.f);
                *(u16x4*)(hbuf + SWI(rA, nt * 16 + nb)) = o;
            }
            xc = xn; yc = yn;
        }
    }

    // ---- layers (wave-local, swapped orientation) ----
    gnn_layer_sw(hbuf, msgbuf, w02t1, wsf + 14368, n1g, n1b, nc, vmask, b0, g, c);
    gnn_layer_sw(hbuf, msgbuf, w02t2, wsf + 14432, n2g, n2b, nc, vmask, b0, g, c);

    // ---- g = masked mean; writes msgbuf (bf16) + out4 (f32) ----
    wave_mean(hbuf, msgbuf, out + OUT4, nc, b0, g, c);

    // ---- q + heads (original orientation; D rows = batches) ----
    {
        bf8 a0 = LD8(msgbuf, (c & 3), 0 + g);
        bf8 a1 = LD8(msgbuf, (c & 3), 4 + g);
        f32x4 dq[4];
        #pragma unroll
        for (int nt = 0; nt < 4; ++nt) dq[nt] = (f32x4){0.f, 0.f, 0.f, 0.f};
        #pragma unroll
        for (int nt = 0; nt < 4; ++nt) {
            const unsigned short* wp = pqt + (nt * 16 + c) * 64 + g * 8;
            dq[nt] = MFMA16(a0, *(const bf8*)(wp), dq[nt], 0, 0, 0);
            dq[nt] = MFMA16(a1, *(const bf8*)(wp + 32), dq[nt], 0, 0, 0);
        }
        f32x4 dh[2];
        #pragma unroll
        for (int nt = 0; nt < 2; ++nt) dh[nt] = (f32x4){0.f, 0.f, 0.f, 0.f};
        #pragma unroll
        for (int nt = 0; nt < 2; ++nt) {
            const unsigned short* wp = hdt + (nt * 16 + c) * 64 + g * 8;
            dh[nt] = MFMA16(a0, *(const bf8*)(wp), dh[nt], 0, 0, 0);
            dh[nt] = MFMA16(a1, *(const bf8*)(wp + 32), dh[nt], 0, 0, 0);
        }
        if (g == 0) {   // D rows 0..3 = this wave's batches r
            #pragma unroll
            for (int r = 0; r < 4; ++r) {
                #pragma unroll
                for (int nt = 0; nt < 4; ++nt)
                    qbuf[r * 68 + nt * 16 + c] = dq[nt][r] + pqb[nt * 16 + c];
                size_t ob = (size_t)(b0 + r);
                #pragma unroll
                for (int nt = 0; nt < 2; ++nt) {
                    int col = nt * 16 + c;
                    float v = dh[nt][r] + headb[col];
                    if (col < 8)       out[ob * 8 + col] = v;
                    else if (col < 18) out[OUT1 + ob * 10 + (col - 8)] = v;
                    else if (col < 28) out[OUT2 + ob * 10 + (col - 18)] = v;
                }
            }
        }
    }

    // ---- pk (swapped) fused with pl = q.k: lane owns row rA ----
    {
        f32x4 pkb4[4];
        #pragma unroll
        for (int nt = 0; nt < 4; ++nt) pkb4[nt] = *(const f32x4*)(pkb + nt * 16 + nb);
        #pragma unroll 1
        for (int mt = 0; mt < 5; ++mt) {
            int rA = mt * 16 + c;
            int bA = (rA >= 20) + (rA >= 40) + (rA >= 60);
            bf8 h0 = LD8(hbuf, rA, 0 + g);
            bf8 h1 = LD8(hbuf, rA, 4 + g);
            f32x4 dk[4];
            #pragma unroll
            for (int nt = 0; nt < 4; ++nt) dk[nt] = (f32x4){0.f, 0.f, 0.f, 0.f};
            #pragma unroll
            for (int nt = 0; nt < 4; ++nt) {
                const unsigned short* wp = pkt + (nt * 16 + c) * 64 + g * 8;
                dk[nt] = MFMA16(*(const bf8*)(wp), h0, dk[nt], 0, 0, 0);     // swapped
                dk[nt] = MFMA16(*(const bf8*)(wp + 32), h1, dk[nt], 0, 0, 0);
            }
            float pl = 0.f;
            #pragma unroll
            for (int nt = 0; nt < 4; ++nt) {
                f32x4 q4 = *(const f32x4*)(&qbuf[bA * 68 + nt * 16 + nb]);
                #pragma unroll
                for (int r = 0; r < 4; ++r)
                    pl = fmaf(dk[nt][r] + pkb4[nt][r], q4[r], pl);
            }
            pl += __shfl_xor(pl, 16, 64);
            pl += __shfl_xor(pl, 32, 64);
            if (g == 0) {
                bool valid = (vmask >> mt) & 1u;
                out[OUT3 + (size_t)(grow0 + rA)] = valid ? pl : -1e9f;
            }
        }
    }
}

extern "C" void kernel_launch(void* const* d_in, const int* in_sizes, int n_in,
                              void* d_out, int out_size, void* d_ws, size_t ws_size,
                              hipStream_t stream) {
    const float* nf   = (const float*)d_in[0];
    const int*   nn_c = (const int*)d_in[1];
    const float* neW  = (const float*)d_in[2];
    const float* ne_b = (const float*)d_in[3];
    const float* neA  = (const float*)d_in[4];
    const float* neB  = (const float*)d_in[5];
    const float* g1W0 = (const float*)d_in[6];
    const float* g1b0 = (const float*)d_in[7];
    const float* g1A  = (const float*)d_in[8];
    const float* g1B  = (const float*)d_in[9];
    const float* g1W2 = (const float*)d_in[10];
    const float* g1b2 = (const float*)d_in[11];
    const float* g2W0 = (const float*)d_in[12];
    const float* g2b0 = (const float*)d_in[13];
    const float* g2A  = (const float*)d_in[14];
    const float* g2B  = (const float*)d_in[15];
    const float* g2W2 = (const float*)d_in[16];
    const float* g2b2 = (const float*)d_in[17];
    const float* n1g  = (const float*)d_in[18];
    const float* n1b  = (const float*)d_in[19];
    const float* n2g  = (const float*)d_in[20];
    const float* n2b  = (const float*)d_in[21];
    const float* ohW  = (const float*)d_in[22];
    const float* ohb  = (const float*)d_in[23];
    const float* c1W  = (const float*)d_in[24];
    const float* c1b  = (const float*)d_in[25];
    const float* c2W  = (const float*)d_in[26];
    const float* c2b  = (const float*)d_in[27];
    const float* pqW  = (const float*)d_in[28];
    const float* pqb  = (const float*)d_in[29];
    const float* pkW  = (const float*)d_in[30];
    const float* pkb  = (const float*)d_in[31];
    unsigned short* ws = (unsigned short*)d_ws;
    float* out = (float*)d_out;

    merge_all<<<113, 256, 0, stream>>>(neW, neA, neB, ne_b,
                                       g1W0, g1A, g1B, g1W2, g1b0, g1b2,
                                       g2W0, g2A, g2B, g2W2, g2b0, g2b2,
                                       pkW, pqW, ohW, c1W, c2W,
                                       ohb, c1b, c2b, ws);
    gnn_main<<<BATCH / 4, 64, 0, stream>>>(nf, nn_c, ws,
                                           n1g, n1b, n2g, n2b,
                                           pqb, pkb, out);
}

// Round 13
// 102.790 us; speedup vs baseline: 1.0558x; 1.0082x over previous
//
#include <hip/hip_runtime.h>

static constexpr int BATCH = 32768;

typedef short bf8 __attribute__((ext_vector_type(8)));   // 8 bf16 in 4 VGPRs (MFMA A/B frag)
typedef float f32x4 __attribute__((ext_vector_type(4))); // MFMA C/D frag
typedef unsigned short u16x4 __attribute__((ext_vector_type(4)));

#define MFMA16 __builtin_amdgcn_mfma_f32_16x16x32_bf16

// A[16M x 32K]: lane(g,c) holds row=c, k=g*8+e.  B[32K x 16N]: col=c, k=g*8+e.
// D[16M x 16N]: col=c, row=g*4+r.
// SWAPPED use: mfma(W_frag, h_frag) -> lane(g,c) = u[m=c][n=g*4+r] per n-tile.

__device__ __forceinline__ unsigned short f2bf(float f) {
    return __builtin_bit_cast(unsigned short, static_cast<__bf16>(f));
}
__device__ __forceinline__ float bf2f(unsigned short h) {
    return __uint_as_float(((unsigned)h) << 16);
}

// swizzled u16 index within a [rows][64] bf16 LDS tile (128B rows):
#define SWI(row, col)  ((row) * 64 + ((col) ^ (((row) & 7) << 3)))
#define LD8(buf, row, col8) (*(const bf8*)((buf) + (row) * 64 + 8 * ((col8) ^ ((row) & 7))))

// ---- ws layout (u16 elems): weights [N][K] bf16 ----
// W02 = W0eff @ W2 (no nonlinearity between the two linears)
// [0,2048)        neWt    [64][32]  (k<16: merged neW; k==16: ne_b; else 0)
// [2048,10240)    w02t_1  [64][128]
// [10240,18432)   w02t_2  [64][128]
// [18432,22528)   pkt     [64][64]
// [22528,26624)   pqt     [64][64]
// [26624,28672)   headt   [32][64] (oh|c1|c2 packed, rest 0)
// floats: [14336,14368) headb; [14368,14432) b2eff_1; [14432,14496) b2eff_2
__global__ void __launch_bounds__(256) merge_all(
    const float* __restrict__ neW, const float* __restrict__ neA, const float* __restrict__ neB,
    const float* __restrict__ ne_b,
    const float* __restrict__ g1W0, const float* __restrict__ g1A, const float* __restrict__ g1B,
    const float* __restrict__ g1W2, const float* __restrict__ g1b0, const float* __restrict__ g1b2,
    const float* __restrict__ g2W0, const float* __restrict__ g2A, const float* __restrict__ g2B,
    const float* __restrict__ g2W2, const float* __restrict__ g2b0, const float* __restrict__ g2b2,
    const float* __restrict__ pkW, const float* __restrict__ pqW,
    const float* __restrict__ ohW, const float* __restrict__ c1W, const float* __restrict__ c2W,
    const float* __restrict__ ohb, const float* __restrict__ c1b, const float* __restrict__ c2b,
    unsigned short* __restrict__ ws) {
    int t = blockIdx.x * 256 + threadIdx.x;
    if (t >= 28832) return;
    if (t >= 28768) { // b2eff layer 2
        int n = t - 28768;
        float acc = g2b2[n];
        for (int k = 0; k < 64; ++k) acc = fmaf(g2b0[k], g2W2[k * 64 + n], acc);
        ((float*)ws)[14432 + n] = acc;
        return;
    }
    if (t >= 28704) { // b2eff layer 1
        int n = t - 28704;
        float acc = g1b2[n];
        for (int k = 0; k < 64; ++k) acc = fmaf(g1b0[k], g1W2[k * 64 + n], acc);
        ((float*)ws)[14368 + n] = acc;
        return;
    }
    if (t >= 28672) { // head bias (f32)
        int i = t - 28672;
        float v = 0.0f;
        if (i < 8) v = ohb[i]; else if (i < 18) v = c1b[i - 8]; else if (i < 28) v = c2b[i - 18];
        ((float*)ws)[14336 + i] = v;
        return;
    }
    float val = 0.0f;
    if (t < 2048) {
        int n = t >> 5, k = t & 31;
        if (k < 16) {
            val = neW[k * 64 + n];
            #pragma unroll
            for (int r = 0; r < 4; ++r) val = fmaf(neA[k * 4 + r], neB[r * 64 + n], val);
        } else if (k == 16) {
            val = ne_b[n];
        }
    } else if (t < 18432) {
        // w02t[n][k] = sum_j W0eff[k][j] * W2[j][n]
        int loc = t - 2048;
        const float *W0, *A, *Bm, *W2;
        if (loc < 8192) { W0 = g1W0; A = g1A; Bm = g1B; W2 = g1W2; }
        else { loc -= 8192; W0 = g2W0; A = g2A; Bm = g2B; W2 = g2W2; }
        int n = loc >> 7, k = loc & 127;
        float a0 = A[k * 4 + 0], a1 = A[k * 4 + 1], a2 = A[k * 4 + 2], a3 = A[k * 4 + 3];
        for (int j = 0; j < 64; ++j) {
            float w0e = W0[k * 64 + j];
            w0e = fmaf(a0, Bm[0 * 64 + j], w0e);
            w0e = fmaf(a1, Bm[1 * 64 + j], w0e);
            w0e = fmaf(a2, Bm[2 * 64 + j], w0e);
            w0e = fmaf(a3, Bm[3 * 64 + j], w0e);
            val = fmaf(w0e, W2[j * 64 + n], val);
        }
    } else if (t < 22528) {
        int loc = t - 18432; int n = loc >> 6, k = loc & 63;
        val = pkW[k * 64 + n];
    } else if (t < 26624) {
        int loc = t - 22528; int n = loc >> 6, k = loc & 63;
        val = pqW[k * 64 + n];
    } else {
        int loc = t - 26624; int n = loc >> 6, k = loc & 63;
        if (n < 8) val = ohW[k * 8 + n];
        else if (n < 18) val = c1W[k * 10 + (n - 8)];
        else if (n < 28) val = c2W[k * 10 + (n - 18)];
    }
    ws[t] = f2bf(val);
}

__device__ __forceinline__ int nc_sel(int4 nc, int bb) {
    int lo = (bb & 1) ? nc.y : nc.x;
    int hi = (bb & 1) ? nc.w : nc.z;
    return (bb & 2) ? hi : lo;
}

// Per-wave mean over the wave's 4 batches. lane (g,c): batch g, cols 4c..4c+3.
__device__ __forceinline__ void wave_mean(
    const unsigned short* hbuf, unsigned short* msgbuf, float* out4,
    int4 nc, int b0, int g, int c) {
    int c4 = c * 4;
    float s0 = 0, s1 = 0, s2 = 0, s3 = 0;
    int base = g * 20;
    #pragma unroll
    for (int n = 0; n < 20; ++n) {
        int row = base + n;
        u16x4 v = *(const u16x4*)(hbuf + SWI(row, c4));
        s0 += bf2f(v[0]); s1 += bf2f(v[1]); s2 += bf2f(v[2]); s3 += bf2f(v[3]);
    }
    float ic = 1.0f / (float)nc_sel(nc, g);
    s0 *= ic; s1 *= ic; s2 *= ic; s3 *= ic;
    u16x4 o; o[0] = f2bf(s0); o[1] = f2bf(s1); o[2] = f2bf(s2); o[3] = f2bf(s3);
    *(u16x4*)(msgbuf + SWI(g, c4)) = o;
    if (out4) {
        f32x4 fo = {s0, s1, s2, s3};
        *(f32x4*)(out4 + (size_t)(b0 + g) * 64 + c4) = fo;
    }
}

// One GNN layer, swapped orientation: lane (g,c) owns row m=mt*16+c.
// Epilogue reuses du in place (no separate vv array).
__device__ __forceinline__ void gnn_layer_sw(
    unsigned short* hbuf, unsigned short* msgbuf,
    const unsigned short* __restrict__ w02t,
    const float* __restrict__ b2e, const float* __restrict__ gmp, const float* __restrict__ btp,
    int4 nc, unsigned vmask, int b0, int g, int c) {
    wave_mean(hbuf, msgbuf, nullptr, nc, b0, g, c);
    const int nb = g * 4;

    #pragma unroll 1
    for (int mt = 0; mt < 5; ++mt) {
        int rA = mt * 16 + c;
        int bA = (rA >= 20) + (rA >= 40) + (rA >= 60);
        bf8 h0 = LD8(hbuf, rA, 0 + g);
        bf8 h1 = LD8(hbuf, rA, 4 + g);
        bf8 m0 = LD8(msgbuf, bA, 0 + g);
        bf8 m1 = LD8(msgbuf, bA, 4 + g);
        f32x4 du[4];
        #pragma unroll
        for (int nt = 0; nt < 4; ++nt) du[nt] = (f32x4){0.f, 0.f, 0.f, 0.f};
        #pragma unroll
        for (int nt = 0; nt < 4; ++nt) {
            const unsigned short* wp = w02t + (nt * 16 + c) * 128 + g * 8;
            du[nt] = MFMA16(*(const bf8*)(wp), h0, du[nt], 0, 0, 0);      // swapped: A=W
            du[nt] = MFMA16(*(const bf8*)(wp + 32), h1, du[nt], 0, 0, 0);
            du[nt] = MFMA16(*(const bf8*)(wp + 64), m0, du[nt], 0, 0, 0);
            du[nt] = MFMA16(*(const bf8*)(wp + 96), m1, du[nt], 0, 0, 0);
        }
        // epilogue: v = h + relu(u+b2e) overwrites du; LN over row; write h'
        float ps = 0.f, pq = 0.f;
        #pragma unroll
        for (int nt = 0; nt < 4; ++nt) {
            f32x4 b4 = *(const f32x4*)(b2e + nt * 16 + nb);
            u16x4 h4 = *(const u16x4*)(hbuf + SWI(rA, nt * 16 + nb));
            #pragma unroll
            for (int r = 0; r < 4; ++r) {
                float u = du[nt][r] + b4[r];
                float v = bf2f(h4[r]) + fmaxf(u, 0.f);
                du[nt][r] = v;
                ps += v; pq += v * v;
            }
        }
        ps += __shfl_xor(ps, 16, 64); ps += __shfl_xor(ps, 32, 64);
        pq += __shfl_xor(pq, 16, 64); pq += __shfl_xor(pq, 32, 64);
        float mu = ps * 0.015625f;
        float var = pq * 0.015625f - mu * mu;
        float rstd = rsqrtf(var + 1e-5f);
        bool valid = (vmask >> mt) & 1u;
        #pragma unroll
        for (int nt = 0; nt < 4; ++nt) {
            f32x4 g4 = *(const f32x4*)(gmp + nt * 16 + nb);
            f32x4 t4 = *(const f32x4*)(btp + nt * 16 + nb);
            u16x4 o;
            #pragma unroll
            for (int r = 0; r < 4; ++r) {
                float hn = (du[nt][r] - mu) * rstd * g4[r] + t4[r];
                o[r] = f2bf(valid ? hn : 0.f);
            }
            *(u16x4*)(hbuf + SWI(rA, nt * 16 + nb)) = o;
        }
    }
}

__global__ void __launch_bounds__(64, 5) gnn_main(
    const float* __restrict__ nf, const int* __restrict__ nn_c,
    const unsigned short* __restrict__ W,
    const float* __restrict__ n1g, const float* __restrict__ n1b,
    const float* __restrict__ n2g, const float* __restrict__ n2b,
    const float* __restrict__ pqb, const float* __restrict__ pkb,
    float* __restrict__ out) {
    __shared__ __align__(16) unsigned short hbuf[80 * 64];
    __shared__ __align__(16) unsigned short msgbuf[4 * 64];
    __shared__ __align__(16) float qbuf[4 * 68];   // f32, row stride 68 (bank-spread)

    const int lane = threadIdx.x & 63;
    const int g = lane >> 4, c = lane & 15;
    const int nb = g * 4;
    const int b0 = blockIdx.x * 4;
    const long grow0 = (long)b0 * 20;

    const unsigned short* neWt  = W;
    const unsigned short* w02t1 = W + 2048;
    const unsigned short* w02t2 = W + 10240;
    const unsigned short* pkt   = W + 18432;
    const unsigned short* pqt   = W + 22528;
    const unsigned short* hdt   = W + 26624;
    const float* wsf = (const float*)W;
    const float* headb = wsf + 14336;

    const size_t OUT1 = (size_t)BATCH * 8,  OUT2 = (size_t)BATCH * 18;
    const size_t OUT3 = (size_t)BATCH * 28, OUT4 = (size_t)BATCH * 48;

    int4 nc;
    nc.x = nn_c[b0 + 0]; nc.y = nn_c[b0 + 1];
    nc.z = nn_c[b0 + 2]; nc.w = nn_c[b0 + 3];

    unsigned vmask = 0;   // bit mt: row mt*16+c valid

    // ---- embed (swapped), 2-deep nf load prefetch ----
    {
        bf8 bne[4];
        #pragma unroll
        for (int nt = 0; nt < 4; ++nt)
            bne[nt] = *(const bf8*)(neWt + (nt * 16 + c) * 32 + g * 8);
        f32x4 xc = (f32x4){0.f, 0.f, 0.f, 0.f}, yc = xc, xn = xc, yn = xc;
        if (g < 2) {
            const f32x4* p4 = (const f32x4*)(nf + (grow0 + c) * 16 + g * 8);
            xc = p4[0]; yc = p4[1];
        }
        #pragma unroll 1
        for (int mt = 0; mt < 5; ++mt) {
            int rA = mt * 16 + c;
            int bq = (rA >= 20) + (rA >= 40) + (rA >= 60);
            if (mt < 4 && g < 2) {
                const f32x4* p4 = (const f32x4*)(nf + (grow0 + rA + 16) * 16 + g * 8);
                xn = p4[0]; yn = p4[1];
            }
            bf8 b = (bf8){0, 0, 0, 0, 0, 0, 0, 0};
            if (g < 2) {
                b[0] = (short)f2bf(xc[0]); b[1] = (short)f2bf(xc[1]);
                b[2] = (short)f2bf(xc[2]); b[3] = (short)f2bf(xc[3]);
                b[4] = (short)f2bf(yc[0]); b[5] = (short)f2bf(yc[1]);
                b[6] = (short)f2bf(yc[2]); b[7] = (short)f2bf(yc[3]);
            } else if (g == 2) {
                b[0] = (short)0x3F80;  // k=16 row: +ne_b
            }
            f32x4 acc[4];
            #pragma unroll
            for (int nt = 0; nt < 4; ++nt) acc[nt] = (f32x4){0.f, 0.f, 0.f, 0.f};
            #pragma unroll
            for (int nt = 0; nt < 4; ++nt) acc[nt] = MFMA16(bne[nt], b, acc[nt], 0, 0, 0); // swapped
            bool valid = (rA - bq * 20) < nc_sel(nc, bq);
            vmask |= (valid ? 1u : 0u) << mt;
            #pragma unroll
            for (int nt = 0; nt < 4; ++nt) {
                u16x4 o;
                #pragma unroll
                for (int r = 0; r < 4; ++r) o[r] = f2bf(valid ? acc[nt][r] : 0.f);
                *(u16x4*)(hbuf + SWI(rA, nt * 16 + nb)) = o;
            }
            xc = xn; yc = yn;
        }
    }

    // ---- layers (wave-local, swapped orientation) ----
    gnn_layer_sw(hbuf, msgbuf, w02t1, wsf + 14368, n1g, n1b, nc, vmask, b0, g, c);
    gnn_layer_sw(hbuf, msgbuf, w02t2, wsf + 14432, n2g, n2b, nc, vmask, b0, g, c);

    // ---- g = masked mean; writes msgbuf (bf16) + out4 (f32) ----
    wave_mean(hbuf, msgbuf, out + OUT4, nc, b0, g, c);

    // ---- q + heads (original orientation; D rows = batches) ----
    {
        bf8 a0 = LD8(msgbuf, (c & 3), 0 + g);
        bf8 a1 = LD8(msgbuf, (c & 3), 4 + g);
        f32x4 dq[4];
        #pragma unroll
        for (int nt = 0; nt < 4; ++nt) dq[nt] = (f32x4){0.f, 0.f, 0.f, 0.f};
        #pragma unroll
        for (int nt = 0; nt < 4; ++nt) {
            const unsigned short* wp = pqt + (nt * 16 + c) * 64 + g * 8;
            dq[nt] = MFMA16(a0, *(const bf8*)(wp), dq[nt], 0, 0, 0);
            dq[nt] = MFMA16(a1, *(const bf8*)(wp + 32), dq[nt], 0, 0, 0);
        }
        f32x4 dh[2];
        #pragma unroll
        for (int nt = 0; nt < 2; ++nt) dh[nt] = (f32x4){0.f, 0.f, 0.f, 0.f};
        #pragma unroll
        for (int nt = 0; nt < 2; ++nt) {
            const unsigned short* wp = hdt + (nt * 16 + c) * 64 + g * 8;
            dh[nt] = MFMA16(a0, *(const bf8*)(wp), dh[nt], 0, 0, 0);
            dh[nt] = MFMA16(a1, *(const bf8*)(wp + 32), dh[nt], 0, 0, 0);
        }
        if (g == 0) {   // D rows 0..3 = this wave's batches r
            #pragma unroll
            for (int r = 0; r < 4; ++r) {
                #pragma unroll
                for (int nt = 0; nt < 4; ++nt)
                    qbuf[r * 68 + nt * 16 + c] = dq[nt][r] + pqb[nt * 16 + c];
                size_t ob = (size_t)(b0 + r);
                #pragma unroll
                for (int nt = 0; nt < 2; ++nt) {
                    int col = nt * 16 + c;
                    float v = dh[nt][r] + headb[col];
                    if (col < 8)       out[ob * 8 + col] = v;
                    else if (col < 18) out[OUT1 + ob * 10 + (col - 8)] = v;
                    else if (col < 28) out[OUT2 + ob * 10 + (col - 18)] = v;
                }
            }
        }
    }

    // ---- pk (swapped) fused with pl = q.k: lane owns row rA ----
    {
        #pragma unroll 1
        for (int mt = 0; mt < 5; ++mt) {
            int rA = mt * 16 + c;
            int bA = (rA >= 20) + (rA >= 40) + (rA >= 60);
            bf8 h0 = LD8(hbuf, rA, 0 + g);
            bf8 h1 = LD8(hbuf, rA, 4 + g);
            f32x4 dk[4];
            #pragma unroll
            for (int nt = 0; nt < 4; ++nt) dk[nt] = (f32x4){0.f, 0.f, 0.f, 0.f};
            #pragma unroll
            for (int nt = 0; nt < 4; ++nt) {
                const unsigned short* wp = pkt + (nt * 16 + c) * 64 + g * 8;
                dk[nt] = MFMA16(*(const bf8*)(wp), h0, dk[nt], 0, 0, 0);     // swapped
                dk[nt] = MFMA16(*(const bf8*)(wp + 32), h1, dk[nt], 0, 0, 0);
            }
            float pl = 0.f;
            #pragma unroll
            for (int nt = 0; nt < 4; ++nt) {
                f32x4 q4 = *(const f32x4*)(&qbuf[bA * 68 + nt * 16 + nb]);
                f32x4 p4 = *(const f32x4*)(pkb + nt * 16 + nb);
                #pragma unroll
                for (int r = 0; r < 4; ++r)
                    pl = fmaf(dk[nt][r] + p4[r], q4[r], pl);
            }
            pl += __shfl_xor(pl, 16, 64);
            pl += __shfl_xor(pl, 32, 64);
            if (g == 0) {
                bool valid = (vmask >> mt) & 1u;
                out[OUT3 + (size_t)(grow0 + rA)] = valid ? pl : -1e9f;
            }
        }
    }
}

extern "C" void kernel_launch(void* const* d_in, const int* in_sizes, int n_in,
                              void* d_out, int out_size, void* d_ws, size_t ws_size,
                              hipStream_t stream) {
    const float* nf   = (const float*)d_in[0];
    const int*   nn_c = (const int*)d_in[1];
    const float* neW  = (const float*)d_in[2];
    const float* ne_b = (const float*)d_in[3];
    const float* neA  = (const float*)d_in[4];
    const float* neB  = (const float*)d_in[5];
    const float* g1W0 = (const float*)d_in[6];
    const float* g1b0 = (const float*)d_in[7];
    const float* g1A  = (const float*)d_in[8];
    const float* g1B  = (const float*)d_in[9];
    const float* g1W2 = (const float*)d_in[10];
    const float* g1b2 = (const float*)d_in[11];
    const float* g2W0 = (const float*)d_in[12];
    const float* g2b0 = (const float*)d_in[13];
    const float* g2A  = (const float*)d_in[14];
    const float* g2B  = (const float*)d_in[15];
    const float* g2W2 = (const float*)d_in[16];
    const float* g2b2 = (const float*)d_in[17];
    const float* n1g  = (const float*)d_in[18];
    const float* n1b  = (const float*)d_in[19];
    const float* n2g  = (const float*)d_in[20];
    const float* n2b  = (const float*)d_in[21];
    const float* ohW  = (const float*)d_in[22];
    const float* ohb  = (const float*)d_in[23];
    const float* c1W  = (const float*)d_in[24];
    const float* c1b  = (const float*)d_in[25];
    const float* c2W  = (const float*)d_in[26];
    const float* c2b  = (const float*)d_in[27];
    const float* pqW  = (const float*)d_in[28];
    const float* pqb  = (const float*)d_in[29];
    const float* pkW  = (const float*)d_in[30];
    const float* pkb  = (const float*)d_in[31];
    unsigned short* ws = (unsigned short*)d_ws;
    float* out = (float*)d_out;

    merge_all<<<113, 256, 0, stream>>>(neW, neA, neB, ne_b,
                                       g1W0, g1A, g1B, g1W2, g1b0, g1b2,
                                       g2W0, g2A, g2B, g2W2, g2b0, g2b2,
                                       pkW, pqW, ohW, c1W, c2W,
                                       ohb, c1b, c2b, ws);
    gnn_main<<<BATCH / 4, 64, 0, stream>>>(nf, nn_c, ws,
                                           n1g, n1b, n2g, n2b,
                                           pqb, pkb, out);
}